// Round 1
// baseline (547.759 us; speedup 1.0000x reference)
//
#include <hip/hip_runtime.h>
#include <hip/hip_bf16.h>
#include <math.h>

#define B_N 4096
#define M_N 128
#define F_N 32
#define H_N 512
#define NFM 4096   // F*M

// wave-local LDS sync: all lanes of a wave run in lockstep, so a waitcnt on
// outstanding LDS ops makes prior cross-lane LDS writes visible to reads.
#define WAVE_SYNC() do { \
  asm volatile("s_waitcnt lgkmcnt(0)" ::: "memory"); \
  __builtin_amdgcn_sched_barrier(0); \
} while (0)

// ---------------------------------------------------------------------------
// Kernel 1: occupied-index extraction (wave ballot, parallel) + hidden layer
//   h[b,:] = tanhf( sum_j W1[idx_j,:] + b1 )   (ascending-j chain, fp32)
// ---------------------------------------------------------------------------
__global__ __launch_bounds__(256) void k1_idx_h(
    const float* __restrict__ n, const float* __restrict__ W1,
    const float* __restrict__ b1, float* __restrict__ h_ws,
    int* __restrict__ idx_ws)
{
  __shared__ int s_idx[F_N];
  __shared__ int s_cnt0;
  const int b = blockIdx.x;
  const int t = threadIdx.x;

  bool p = false;
  int before = 0;
  if (t < 128) {
    float v = n[(size_t)b * M_N + t];
    p = v > 0.5f;
    unsigned long long m = __ballot(p);
    int lane = t & 63;
    before = __popcll(m & ((1ull << lane) - 1ull));
    if (t < 64) {
      if (lane == 0) s_cnt0 = __popcll(m);
      if (p) s_idx[before] = t;          // ascending within wave 0
    }
  }
  __syncthreads();
  if (t >= 64 && t < 128 && p) s_idx[s_cnt0 + before] = t;
  __syncthreads();

  if (t < F_N) idx_ws[b * F_N + t] = s_idx[t];

  #pragma unroll
  for (int cc = 0; cc < 2; ++cc) {
    int c = t + cc * 256;
    float acc = 0.0f;
    #pragma unroll
    for (int j = 0; j < F_N; ++j)
      acc += W1[(size_t)s_idx[j] * H_N + c];
    acc += b1[c];                        // b1 = zeros: exact
    h_ws[(size_t)b * H_N + c] = tanhf(acc);
  }
}

// ---------------------------------------------------------------------------
// Kernel 2: tiled fp32 GEMM  bf = h @ W2.
// ROUND 12 change: 256x128 block tile, 16x8 micro-tile, BK=16.
//   Rationale: the 8x8 micro-tile demanded 1 B of LDS per fma (4 ds_read_b128
//   per 64 fma) = 100%+ of the 128 B/cy/CU LDS read bandwidth at VALU peak,
//   making LDS the limiter (VALUBusy 60%). 16x8 reads 6 ds_read_b128 per
//   128 fma (0.75 B/fma, 75% of LDS peak) -> VALU becomes the sole limiter.
//   BK halved to 16 keeps the double-buffered LDS at 49664 B so 2 blocks/CU
//   (8 waves/CU) survive. __launch_bounds__(256,2) caps VGPR alloc at 256.
// Structure unchanged: T14 register-prefetch + LDS double buffer, ONE barrier
//   per k-tile (stage-writes go to the idle buffer).
//   At TRANSPOSED [kk][r] stride 260: bank (4*kA + r) % 32 spreads stage
//   writes; frag reads are 16-lane broadcasts (conflict-free).
//   Bs [16][128]: frag reads at tx*4 / tx*4+64 are 2-way alias = free.
// ARITHMETIC BIT-IDENTICAL to rounds 6-11: each output = one ascending-k
// fmaf chain (k=0..511, tiles ascending, kk ascending) in a single
// accumulator; epilogue expression Phi + (Ds + b2) unchanged.
// ---------------------------------------------------------------------------
__global__ __launch_bounds__(256, 2) void k2_gemm_gather(
    const float* __restrict__ h, const float* __restrict__ W2,
    const float* __restrict__ b2, const float* __restrict__ Phi,
    const int* __restrict__ idx, float* __restrict__ phi)
{
  // per buffer: At [16][260] = 4160 floats, Bs [16][128] = 2048 floats
  __shared__ __align__(16) float smem[2 * 6208];   // 49664 B

  const int tid = threadIdx.x;
  const int s0 = blockIdx.x * 256;           // 256 batch rows per block
  const int ig = blockIdx.y;                 // fermion row, 0..31
  const int n0 = ig * 128;
  const int tx = tid & 15;                   // col group: cols tx*4, 64+tx*4
  const int ty = tid >> 4;                   // row group 0..15
  const int kA = tid & 15;                   // A stage: kk (0..15)
  const int rbA = (tid >> 4) * 16;           // A stage: row block base (0..240)
  const int kB = tid >> 5;                   // B stage: k row (0..7)
  const int cB = (tid & 31) * 4;             // B stage: col*4

  float acc[16][8];
  #pragma unroll
  for (int i = 0; i < 16; ++i)
    #pragma unroll
    for (int u = 0; u < 8; ++u) acc[i][u] = 0.f;

  float  aReg[16];
  float4 bReg[2];

  // ---- prologue: stage tile 0 into buf0 ----
  #pragma unroll
  for (int u = 0; u < 4; ++u)
    #pragma unroll
    for (int i = 0; i < 4; ++i)
      aReg[u * 4 + i] = h[(size_t)(s0 + rbA + u * 4 + i) * H_N + kA];
  #pragma unroll
  for (int u = 0; u < 2; ++u)
    bReg[u] = *(const float4*)&W2[(size_t)(kB + 8 * u) * NFM + n0 + cB];
  #pragma unroll
  for (int u = 0; u < 4; ++u)
    *(float4*)&smem[kA * 260 + rbA + u * 4] =
        make_float4(aReg[4 * u], aReg[4 * u + 1], aReg[4 * u + 2], aReg[4 * u + 3]);
  #pragma unroll
  for (int u = 0; u < 2; ++u)
    *(float4*)&smem[4160 + (kB + 8 * u) * 128 + cB] = bReg[u];
  __syncthreads();

  #pragma unroll 1
  for (int t = 0; t < 32; ++t) {
    float* Atc = smem + (t & 1) * 6208;
    float* Bsc = Atc + 4160;
    float* Atn = smem + ((t + 1) & 1) * 6208;
    float* Bsn = Atn + 4160;

    // issue next tile's global loads (latency hides under compute)
    if (t < 31) {
      int k0n = (t + 1) * 16;
      #pragma unroll
      for (int u = 0; u < 4; ++u)
        #pragma unroll
        for (int i = 0; i < 4; ++i)
          aReg[u * 4 + i] = h[(size_t)(s0 + rbA + u * 4 + i) * H_N + k0n + kA];
      #pragma unroll
      for (int u = 0; u < 2; ++u)
        bReg[u] = *(const float4*)&W2[(size_t)(k0n + kB + 8 * u) * NFM + n0 + cB];
    }

    // compute tile t: 6 x ds_read_b128 + 128 fmaf per kk
    #pragma unroll 4
    for (int kk = 0; kk < 16; ++kk) {
      float4 a0 = *(const float4*)&Atc[kk * 260 + ty * 8];
      float4 a1 = *(const float4*)&Atc[kk * 260 + ty * 8 + 4];
      float4 a2 = *(const float4*)&Atc[kk * 260 + 128 + ty * 8];
      float4 a3 = *(const float4*)&Atc[kk * 260 + 128 + ty * 8 + 4];
      float4 b0 = *(const float4*)&Bsc[kk * 128 + tx * 4];
      float4 b1 = *(const float4*)&Bsc[kk * 128 + tx * 4 + 64];
      float a[16] = {a0.x, a0.y, a0.z, a0.w, a1.x, a1.y, a1.z, a1.w,
                     a2.x, a2.y, a2.z, a2.w, a3.x, a3.y, a3.z, a3.w};
      float bb[8] = {b0.x, b0.y, b0.z, b0.w, b1.x, b1.y, b1.z, b1.w};
      #pragma unroll
      for (int i = 0; i < 16; ++i)
        #pragma unroll
        for (int u = 0; u < 8; ++u)
          acc[i][u] = fmaf(a[i], bb[u], acc[i][u]);
    }

    // stage tile t+1 into the idle buffer; single barrier flips
    if (t < 31) {
      #pragma unroll
      for (int u = 0; u < 4; ++u)
        *(float4*)&Atn[kA * 260 + rbA + u * 4] =
            make_float4(aReg[4 * u], aReg[4 * u + 1], aReg[4 * u + 2], aReg[4 * u + 3]);
      #pragma unroll
      for (int u = 0; u < 2; ++u)
        *(float4*)&Bsn[(kB + 8 * u) * 128 + cB] = bReg[u];
      __syncthreads();
    }
  }

  // epilogue: 8 quarters of 32 rows through buf0 (disjoint from buf1, which
  // laggard waves may still be reading for tile 31: 31&1 == 1)
  // thread rows: i<8 -> ty*8+i (half 0), i>=8 -> 128+ty*8+(i-8) (half 1)
  // quarter q: rows q*32..q*32+31; half = q>>2, owner waves: (ty>>2)==(q&3)
  float* Ds = smem;                          // [32][132] = 4224 floats < 6208
  #pragma unroll 1
  for (int q = 0; q < 8; ++q) {
    if ((ty >> 2) == (q & 3)) {
      int io = (q >> 2) * 8;                 // acc row offset for this half
      int r8 = (ty & 3) * 8;
      #pragma unroll
      for (int i = 0; i < 8; ++i) {
        *(float4*)&Ds[(r8 + i) * 132 + tx * 4] =
            make_float4(acc[io + i][0], acc[io + i][1], acc[io + i][2], acc[io + i][3]);
        *(float4*)&Ds[(r8 + i) * 132 + tx * 4 + 64] =
            make_float4(acc[io + i][4], acc[io + i][5], acc[io + i][6], acc[io + i][7]);
      }
    }
    __syncthreads();
    #pragma unroll
    for (int u = 0; u < 4; ++u) {
      int lin = u * 256 + tid;
      int r = lin >> 5, j = lin & 31;
      int b = s0 + q * 32 + r;
      int c = idx[b * F_N + j];
      float val = Phi[ig * M_N + c] + (Ds[r * 132 + c] + b2[n0 + c]);
      phi[(size_t)b * (F_N * F_N) + ig * F_N + j] = val;
    }
    __syncthreads();
  }
}

// ---------------------------------------------------------------------------
// Kernel 3: batched 32x32 fp32 LU replicating LAPACK sgetf2 exactly.
// Each matrix is owned by ONE wave working in its private LDS slice, so all
// cross-wave __syncthreads() are replaced with wave-local WAVE_SYNC()
// (s_waitcnt lgkmcnt(0)): the 4 waves per block run fully decoupled.
// Arithmetic sequence per matrix UNCHANGED from rounds 6-11.
// PLANAR complex output: out[0..B-1] = log|det|, out[B..2B-1] = arg(sign)
// ---------------------------------------------------------------------------
__global__ __launch_bounds__(256) void k3_det(
    const float* __restrict__ phi, float* __restrict__ out)
{
  __shared__ float A[4][32 * 33];
  const int w = threadIdx.x >> 6;
  const int lane = threadIdx.x & 63;
  const int b = blockIdx.x * 4 + w;
  float* Aw = A[w];

  #pragma unroll
  for (int u = 0; u < 16; ++u) {
    int lin = u * 64 + lane;
    Aw[(lin >> 5) * 33 + (lin & 31)] = phi[(size_t)b * 1024 + lin];
  }
  WAVE_SYNC();

  float logabs = 0.f;
  int negs = 0;
  for (int k = 0; k < 32; ++k) {
    // isamax over rows k..31 of column k (ties -> first index)
    float v = -1.f;
    int vi = lane;
    if (lane >= k && lane < 32) v = fabsf(Aw[lane * 33 + k]);
    #pragma unroll
    for (int off = 32; off > 0; off >>= 1) {
      float ov = __shfl_xor(v, off);
      int oi = __shfl_xor(vi, off);
      if (ov > v || (ov == v && oi < vi)) { v = ov; vi = oi; }
    }
    int p = vi;                          // uniform across the wave
    if (p != k) {
      negs ^= 1;
      if (lane < 32) {
        float tmp = Aw[k * 33 + lane];
        Aw[k * 33 + lane] = Aw[p * 33 + lane];
        Aw[p * 33 + lane] = tmp;
      }
    }
    WAVE_SYNC();
    float piv = Aw[k * 33 + k];
    if (piv < 0.f) negs ^= 1;
    logabs += logf(fabsf(piv));
    if (lane > k && lane < 32) {
      float l = Aw[lane * 33 + k];
      if (fabsf(piv) >= 1.17549435e-38f) l = l * (1.0f / piv);  // sscal path
      else                               l = l / piv;           // tiny pivot
      Aw[lane * 33 + k] = l;
    }
    WAVE_SYNC();
    if (lane > k && lane < 32) {
      int j = lane;
      float nukj = -Aw[k * 33 + j];
      for (int i = k + 1; i < 32; ++i)
        Aw[i * 33 + j] = fmaf(nukj, Aw[i * 33 + k], Aw[i * 33 + j]);
    }
    WAVE_SYNC();
  }

  if (lane == 0) {
    out[b]       = logabs;                                   // Re: log|det|
    out[B_N + b] = (negs & 1) ? 3.14159265358979f : 0.0f;    // Im: arg(sign)
  }
}

// ---------------------------------------------------------------------------
extern "C" void kernel_launch(void* const* d_in, const int* in_sizes, int n_in,
                              void* d_out, int out_size, void* d_ws, size_t ws_size,
                              hipStream_t stream) {
  const float* n   = (const float*)d_in[0];
  const float* Phi = (const float*)d_in[1];
  const float* W1  = (const float*)d_in[2];
  const float* b1  = (const float*)d_in[3];
  const float* W2  = (const float*)d_in[4];
  const float* b2  = (const float*)d_in[5];
  float* out = (float*)d_out;

  char* ws = (char*)d_ws;
  float* h_ws   = (float*)ws;                                   // 8 MB
  int*   idx_ws = (int*)(ws + (size_t)B_N * H_N * 4);           // 512 KB
  float* phi_ws = (float*)(ws + (size_t)B_N * H_N * 4
                              + (size_t)B_N * F_N * 4);         // 16 MB

  hipLaunchKernelGGL(k1_idx_h, dim3(B_N), dim3(256), 0, stream,
                     n, W1, b1, h_ws, idx_ws);
  hipLaunchKernelGGL(k2_gemm_gather, dim3(B_N / 256, F_N), dim3(256), 0, stream,
                     h_ws, W2, b2, Phi, idx_ws, phi_ws);
  hipLaunchKernelGGL(k3_det, dim3(B_N / 4), dim3(256), 0, stream,
                     phi_ws, out);
}

// Round 2
// 291.208 us; speedup vs baseline: 1.8810x; 1.8810x over previous
//
#include <hip/hip_runtime.h>
#include <hip/hip_bf16.h>
#include <math.h>

#define B_N 4096
#define M_N 128
#define F_N 32
#define H_N 512
#define NFM 4096   // F*M

// wave-local LDS sync: all lanes of a wave run in lockstep, so a waitcnt on
// outstanding LDS ops makes prior cross-lane LDS writes visible to reads.
#define WAVE_SYNC() do { \
  asm volatile("s_waitcnt lgkmcnt(0)" ::: "memory"); \
  __builtin_amdgcn_sched_barrier(0); \
} while (0)

// ---------------------------------------------------------------------------
// Kernel 1: occupied-index extraction (wave ballot, parallel) + hidden layer
//   h[b,:] = tanhf( sum_j W1[idx_j,:] + b1 )   (ascending-j chain, fp32)
// ---------------------------------------------------------------------------
__global__ __launch_bounds__(256) void k1_idx_h(
    const float* __restrict__ n, const float* __restrict__ W1,
    const float* __restrict__ b1, float* __restrict__ h_ws,
    int* __restrict__ idx_ws)
{
  __shared__ int s_idx[F_N];
  __shared__ int s_cnt0;
  const int b = blockIdx.x;
  const int t = threadIdx.x;

  bool p = false;
  int before = 0;
  if (t < 128) {
    float v = n[(size_t)b * M_N + t];
    p = v > 0.5f;
    unsigned long long m = __ballot(p);
    int lane = t & 63;
    before = __popcll(m & ((1ull << lane) - 1ull));
    if (t < 64) {
      if (lane == 0) s_cnt0 = __popcll(m);
      if (p) s_idx[before] = t;          // ascending within wave 0
    }
  }
  __syncthreads();
  if (t >= 64 && t < 128 && p) s_idx[s_cnt0 + before] = t;
  __syncthreads();

  if (t < F_N) idx_ws[b * F_N + t] = s_idx[t];

  #pragma unroll
  for (int cc = 0; cc < 2; ++cc) {
    int c = t + cc * 256;
    float acc = 0.0f;
    #pragma unroll
    for (int j = 0; j < F_N; ++j)
      acc += W1[(size_t)s_idx[j] * H_N + c];
    acc += b1[c];                        // b1 = zeros: exact
    h_ws[(size_t)b * H_N + c] = tanhf(acc);
  }
}

// ---------------------------------------------------------------------------
// Kernel 2: tiled fp32 GEMM  bf = h @ W2.
// 256x128 block tile, 16x8 micro-tile, BK=16 (round 12), with the ROUND 13
// fix: the epilogue q-loop is FULLY UNROLLED so every acc[][] access is
// statically indexed. Round 12 used "#pragma unroll 1" + runtime io =
// (q>>2)*8, which made acc[io+i] dynamically indexed -> the compiler demoted
// the whole acc[16][8] array to scratch (VGPR_Count fell to 112, WRITE_SIZE
// exploded 42 MB -> 2.29 GB of scratch traffic, VALUBusy 27%). Rule #20.
// Micro-tile rationale (unchanged): 8x8 demanded 1 B LDS per fma (>= 100% of
// the 128 B/cy/CU LDS read BW at VALU peak, LDS-limited, VALUBusy 60%);
// 16x8 reads 6 ds_read_b128 per 128 fma = 0.75 B/fma -> VALU-limited.
// BK=16 keeps double-buffered LDS at 49664 B -> 2 blocks/CU (8 waves).
// Structure: T14 register-prefetch + LDS double buffer, ONE barrier per
//   k-tile (stage-writes go to the idle buffer).
//   At TRANSPOSED [kk][r] stride 260; Bs [16][128].
// ARITHMETIC BIT-IDENTICAL to rounds 6-12: each output = one ascending-k
// fmaf chain (k=0..511, tiles ascending, kk ascending) in a single
// accumulator; epilogue expression Phi + (Ds + b2) unchanged.
// ---------------------------------------------------------------------------
__global__ __launch_bounds__(256, 2) void k2_gemm_gather(
    const float* __restrict__ h, const float* __restrict__ W2,
    const float* __restrict__ b2, const float* __restrict__ Phi,
    const int* __restrict__ idx, float* __restrict__ phi)
{
  // per buffer: At [16][260] = 4160 floats, Bs [16][128] = 2048 floats
  __shared__ __align__(16) float smem[2 * 6208];   // 49664 B

  const int tid = threadIdx.x;
  const int s0 = blockIdx.x * 256;           // 256 batch rows per block
  const int ig = blockIdx.y;                 // fermion row, 0..31
  const int n0 = ig * 128;
  const int tx = tid & 15;                   // col group: cols tx*4, 64+tx*4
  const int ty = tid >> 4;                   // row group 0..15
  const int kA = tid & 15;                   // A stage: kk (0..15)
  const int rbA = (tid >> 4) * 16;           // A stage: row block base (0..240)
  const int kB = tid >> 5;                   // B stage: k row (0..7)
  const int cB = (tid & 31) * 4;             // B stage: col*4

  float acc[16][8];
  #pragma unroll
  for (int i = 0; i < 16; ++i)
    #pragma unroll
    for (int u = 0; u < 8; ++u) acc[i][u] = 0.f;

  float  aReg[16];
  float4 bReg[2];

  // ---- prologue: stage tile 0 into buf0 ----
  #pragma unroll
  for (int u = 0; u < 4; ++u)
    #pragma unroll
    for (int i = 0; i < 4; ++i)
      aReg[u * 4 + i] = h[(size_t)(s0 + rbA + u * 4 + i) * H_N + kA];
  #pragma unroll
  for (int u = 0; u < 2; ++u)
    bReg[u] = *(const float4*)&W2[(size_t)(kB + 8 * u) * NFM + n0 + cB];
  #pragma unroll
  for (int u = 0; u < 4; ++u)
    *(float4*)&smem[kA * 260 + rbA + u * 4] =
        make_float4(aReg[4 * u], aReg[4 * u + 1], aReg[4 * u + 2], aReg[4 * u + 3]);
  #pragma unroll
  for (int u = 0; u < 2; ++u)
    *(float4*)&smem[4160 + (kB + 8 * u) * 128 + cB] = bReg[u];
  __syncthreads();

  #pragma unroll 1
  for (int t = 0; t < 32; ++t) {
    float* Atc = smem + (t & 1) * 6208;
    float* Bsc = Atc + 4160;
    float* Atn = smem + ((t + 1) & 1) * 6208;
    float* Bsn = Atn + 4160;

    // issue next tile's global loads (latency hides under compute)
    if (t < 31) {
      int k0n = (t + 1) * 16;
      #pragma unroll
      for (int u = 0; u < 4; ++u)
        #pragma unroll
        for (int i = 0; i < 4; ++i)
          aReg[u * 4 + i] = h[(size_t)(s0 + rbA + u * 4 + i) * H_N + k0n + kA];
      #pragma unroll
      for (int u = 0; u < 2; ++u)
        bReg[u] = *(const float4*)&W2[(size_t)(k0n + kB + 8 * u) * NFM + n0 + cB];
    }

    // compute tile t: 6 x ds_read_b128 + 128 fmaf per kk
    #pragma unroll 4
    for (int kk = 0; kk < 16; ++kk) {
      float4 a0 = *(const float4*)&Atc[kk * 260 + ty * 8];
      float4 a1 = *(const float4*)&Atc[kk * 260 + ty * 8 + 4];
      float4 a2 = *(const float4*)&Atc[kk * 260 + 128 + ty * 8];
      float4 a3 = *(const float4*)&Atc[kk * 260 + 128 + ty * 8 + 4];
      float4 b0 = *(const float4*)&Bsc[kk * 128 + tx * 4];
      float4 b1 = *(const float4*)&Bsc[kk * 128 + tx * 4 + 64];
      float a[16] = {a0.x, a0.y, a0.z, a0.w, a1.x, a1.y, a1.z, a1.w,
                     a2.x, a2.y, a2.z, a2.w, a3.x, a3.y, a3.z, a3.w};
      float bb[8] = {b0.x, b0.y, b0.z, b0.w, b1.x, b1.y, b1.z, b1.w};
      #pragma unroll
      for (int i = 0; i < 16; ++i)
        #pragma unroll
        for (int u = 0; u < 8; ++u)
          acc[i][u] = fmaf(a[i], bb[u], acc[i][u]);
    }

    // stage tile t+1 into the idle buffer; single barrier flips
    if (t < 31) {
      #pragma unroll
      for (int u = 0; u < 4; ++u)
        *(float4*)&Atn[kA * 260 + rbA + u * 4] =
            make_float4(aReg[4 * u], aReg[4 * u + 1], aReg[4 * u + 2], aReg[4 * u + 3]);
      #pragma unroll
      for (int u = 0; u < 2; ++u)
        *(float4*)&Bsn[(kB + 8 * u) * 128 + cB] = bReg[u];
      __syncthreads();
    }
  }

  // epilogue: 8 quarters of 32 rows through buf0 (disjoint from buf1, which
  // laggard waves may still be reading for tile 31: 31&1 == 1).
  // FULLY UNROLLED (q compile-time) so acc[][] stays statically indexed and
  // in registers (rule #20 — round 12's runtime io spilled the accumulator).
  // thread rows: i<8 -> ty*8+i (half 0), i>=8 -> 128+ty*8+(i-8) (half 1)
  // quarter q: rows q*32..q*32+31; half = q>>2, owner waves: (ty>>2)==(q&3)
  float* Ds = smem;                          // [32][132] = 4224 floats < 6208
  #pragma unroll
  for (int q = 0; q < 8; ++q) {
    const int io = (q >> 2) * 8;             // compile-time acc row offset
    if ((ty >> 2) == (q & 3)) {
      int r8 = (ty & 3) * 8;
      #pragma unroll
      for (int i = 0; i < 8; ++i) {
        *(float4*)&Ds[(r8 + i) * 132 + tx * 4] =
            make_float4(acc[io + i][0], acc[io + i][1], acc[io + i][2], acc[io + i][3]);
        *(float4*)&Ds[(r8 + i) * 132 + tx * 4 + 64] =
            make_float4(acc[io + i][4], acc[io + i][5], acc[io + i][6], acc[io + i][7]);
      }
    }
    __syncthreads();
    #pragma unroll
    for (int u = 0; u < 4; ++u) {
      int lin = u * 256 + tid;
      int r = lin >> 5, j = lin & 31;
      int b = s0 + q * 32 + r;
      int c = idx[b * F_N + j];
      float val = Phi[ig * M_N + c] + (Ds[r * 132 + c] + b2[n0 + c]);
      phi[(size_t)b * (F_N * F_N) + ig * F_N + j] = val;
    }
    __syncthreads();
  }
}

// ---------------------------------------------------------------------------
// Kernel 3: batched 32x32 fp32 LU replicating LAPACK sgetf2 exactly.
// Each matrix is owned by ONE wave working in its private LDS slice, so all
// cross-wave __syncthreads() are replaced with wave-local WAVE_SYNC()
// (s_waitcnt lgkmcnt(0)): the 4 waves per block run fully decoupled.
// Arithmetic sequence per matrix UNCHANGED from rounds 6-11.
// PLANAR complex output: out[0..B-1] = log|det|, out[B..2B-1] = arg(sign)
// ---------------------------------------------------------------------------
__global__ __launch_bounds__(256) void k3_det(
    const float* __restrict__ phi, float* __restrict__ out)
{
  __shared__ float A[4][32 * 33];
  const int w = threadIdx.x >> 6;
  const int lane = threadIdx.x & 63;
  const int b = blockIdx.x * 4 + w;
  float* Aw = A[w];

  #pragma unroll
  for (int u = 0; u < 16; ++u) {
    int lin = u * 64 + lane;
    Aw[(lin >> 5) * 33 + (lin & 31)] = phi[(size_t)b * 1024 + lin];
  }
  WAVE_SYNC();

  float logabs = 0.f;
  int negs = 0;
  for (int k = 0; k < 32; ++k) {
    // isamax over rows k..31 of column k (ties -> first index)
    float v = -1.f;
    int vi = lane;
    if (lane >= k && lane < 32) v = fabsf(Aw[lane * 33 + k]);
    #pragma unroll
    for (int off = 32; off > 0; off >>= 1) {
      float ov = __shfl_xor(v, off);
      int oi = __shfl_xor(vi, off);
      if (ov > v || (ov == v && oi < vi)) { v = ov; vi = oi; }
    }
    int p = vi;                          // uniform across the wave
    if (p != k) {
      negs ^= 1;
      if (lane < 32) {
        float tmp = Aw[k * 33 + lane];
        Aw[k * 33 + lane] = Aw[p * 33 + lane];
        Aw[p * 33 + lane] = tmp;
      }
    }
    WAVE_SYNC();
    float piv = Aw[k * 33 + k];
    if (piv < 0.f) negs ^= 1;
    logabs += logf(fabsf(piv));
    if (lane > k && lane < 32) {
      float l = Aw[lane * 33 + k];
      if (fabsf(piv) >= 1.17549435e-38f) l = l * (1.0f / piv);  // sscal path
      else                               l = l / piv;           // tiny pivot
      Aw[lane * 33 + k] = l;
    }
    WAVE_SYNC();
    if (lane > k && lane < 32) {
      int j = lane;
      float nukj = -Aw[k * 33 + j];
      for (int i = k + 1; i < 32; ++i)
        Aw[i * 33 + j] = fmaf(nukj, Aw[i * 33 + k], Aw[i * 33 + j]);
    }
    WAVE_SYNC();
  }

  if (lane == 0) {
    out[b]       = logabs;                                   // Re: log|det|
    out[B_N + b] = (negs & 1) ? 3.14159265358979f : 0.0f;    // Im: arg(sign)
  }
}

// ---------------------------------------------------------------------------
extern "C" void kernel_launch(void* const* d_in, const int* in_sizes, int n_in,
                              void* d_out, int out_size, void* d_ws, size_t ws_size,
                              hipStream_t stream) {
  const float* n   = (const float*)d_in[0];
  const float* Phi = (const float*)d_in[1];
  const float* W1  = (const float*)d_in[2];
  const float* b1  = (const float*)d_in[3];
  const float* W2  = (const float*)d_in[4];
  const float* b2  = (const float*)d_in[5];
  float* out = (float*)d_out;

  char* ws = (char*)d_ws;
  float* h_ws   = (float*)ws;                                   // 8 MB
  int*   idx_ws = (int*)(ws + (size_t)B_N * H_N * 4);           // 512 KB
  float* phi_ws = (float*)(ws + (size_t)B_N * H_N * 4
                              + (size_t)B_N * F_N * 4);         // 16 MB

  hipLaunchKernelGGL(k1_idx_h, dim3(B_N), dim3(256), 0, stream,
                     n, W1, b1, h_ws, idx_ws);
  hipLaunchKernelGGL(k2_gemm_gather, dim3(B_N / 256, F_N), dim3(256), 0, stream,
                     h_ws, W2, b2, Phi, idx_ws, phi_ws);
  hipLaunchKernelGGL(k3_det, dim3(B_N / 4), dim3(256), 0, stream,
                     phi_ws, out);
}